// Round 3
// baseline (3396.474 us; speedup 1.0000x reference)
//
#include <hip/hip_runtime.h>

#define B_     2
#define L_     4096
#define DM     1024
#define DI     2048
#define NH     16
#define HD     128
#define NS     64      // D_STATE
#define T_     256     // CHUNK
#define NC     16      // L_/T_
#define CONVD  2176    // DI + 2*NS
#define DPROJ  4240    // DI + CONVD + NH

// ---------------- generic C[m,n] = sum_k A[m,k]*B[n,k] (both row-major) ----------------
__global__ __launch_bounds__(256) void sgemm_abt(
    const float* __restrict__ A, const float* __restrict__ Bm, float* __restrict__ C,
    int M, int N, int K, int lda, int ldb, int ldc)
{
    const int BM = 128, BN = 128, BK = 16;
    __shared__ __align__(16) float As[BK][BM];
    __shared__ __align__(16) float Bs[BK][BN];
    int tid = threadIdx.x;
    int m0 = blockIdx.y * BM;
    int n0 = blockIdx.x * BN;
    int ty = tid / 16, tx = tid % 16;

    float acc[8][8];
    #pragma unroll
    for (int i = 0; i < 8; i++)
        #pragma unroll
        for (int j = 0; j < 8; j++) acc[i][j] = 0.f;

    for (int k0 = 0; k0 < K; k0 += BK) {
        #pragma unroll
        for (int i = 0; i < 2; i++) {
            int f = tid * 2 + i;          // 512 float4 units
            int row = f >> 2;             // 0..127
            int colv = f & 3;             // 0..3
            float4 av = *(const float4*)(A + (size_t)(m0 + row) * lda + k0 + colv * 4);
            As[colv*4+0][row] = av.x; As[colv*4+1][row] = av.y;
            As[colv*4+2][row] = av.z; As[colv*4+3][row] = av.w;
        }
        #pragma unroll
        for (int i = 0; i < 2; i++) {
            int f = tid * 2 + i;
            int row = f >> 2;
            int colv = f & 3;
            float4 bv = make_float4(0.f, 0.f, 0.f, 0.f);
            if (n0 + row < N)
                bv = *(const float4*)(Bm + (size_t)(n0 + row) * ldb + k0 + colv * 4);
            Bs[colv*4+0][row] = bv.x; Bs[colv*4+1][row] = bv.y;
            Bs[colv*4+2][row] = bv.z; Bs[colv*4+3][row] = bv.w;
        }
        __syncthreads();
        #pragma unroll
        for (int kk = 0; kk < BK; kk++) {
            float4 a0 = *(const float4*)&As[kk][ty*8];
            float4 a1 = *(const float4*)&As[kk][ty*8+4];
            // B-frag: two float4 at tx*4 and 64+tx*4 (lane-consecutive -> conflict-free)
            float4 b0 = *(const float4*)&Bs[kk][tx*4];
            float4 b1 = *(const float4*)&Bs[kk][64 + tx*4];
            float a[8] = {a0.x,a0.y,a0.z,a0.w,a1.x,a1.y,a1.z,a1.w};
            float b[8] = {b0.x,b0.y,b0.z,b0.w,b1.x,b1.y,b1.z,b1.w};
            #pragma unroll
            for (int i = 0; i < 8; i++)
                #pragma unroll
                for (int j = 0; j < 8; j++)
                    acc[i][j] = fmaf(a[i], b[j], acc[i][j]);
        }
        __syncthreads();
    }
    #pragma unroll
    for (int i = 0; i < 8; i++) {
        int m = m0 + ty*8 + i;
        #pragma unroll
        for (int j = 0; j < 8; j++) {
            int n = n0 + ((j < 4) ? (tx*4 + j) : (64 + tx*4 + j - 4));
            if (n < N) C[(size_t)m * ldc + n] = acc[i][j];
        }
    }
}

// ---------------- depthwise causal conv (width 4) + bias + silu; one batch (L_ rows) ----------------
__global__ void conv_silu(const float* __restrict__ proj, const float* __restrict__ w,
                          const float* __restrict__ bias, float* __restrict__ xbc)
{
    size_t idx = (size_t)blockIdx.x * 256 + threadIdx.x;
    if (idx >= (size_t)L_ * CONVD) return;
    int c = (int)(idx % CONVD);
    int l = (int)(idx / CONVD);
    float acc = bias[c];
    #pragma unroll
    for (int j = 0; j < 4; j++) {
        int ll = l - 3 + j;
        if (ll >= 0)
            acc = fmaf(proj[(size_t)ll * DPROJ + DI + c], w[c*4+j], acc);
    }
    acc = acc / (1.f + expf(-acc));   // silu
    xbc[(size_t)l * CONVD + c] = acc;
}

// ---------------- dt = softplus(dt_raw + bias); acs = cumsum(dt*A) within chunk ----------------
__global__ __launch_bounds__(256) void dt_scan(
    const float* __restrict__ proj, const float* __restrict__ A_log,
    const float* __restrict__ dt_bias, float* __restrict__ dt_t, float* __restrict__ acs)
{
    int blk = blockIdx.x;            // c*NH + h
    int h = blk % NH;
    int c = blk / NH;
    int t = threadIdx.x;
    size_t row = (size_t)(c * T_ + t);
    float raw = proj[row * DPROJ + DI + CONVD + h] + dt_bias[h];
    float dtv = (raw > 20.f) ? raw : log1pf(expf(raw));
    float Ah = -expf(A_log[h]);
    __shared__ float buf[T_];
    buf[t] = dtv * Ah;
    __syncthreads();
    for (int off = 1; off < T_; off <<= 1) {
        float add = (t >= off) ? buf[t - off] : 0.f;
        __syncthreads();
        buf[t] += add;
        __syncthreads();
    }
    size_t o = (size_t)blk * T_ + t;
    dt_t[o] = dtv;
    acs[o]  = buf[t];
}

// ---------------- per-chunk states[p][n] = sum_t x[t,p]*B[t,n]*exp(acs_last-acs[t])*dt[t] ----------------
__global__ __launch_bounds__(256) void chunk_states(
    const float* __restrict__ xbc, const float* __restrict__ dt_t,
    const float* __restrict__ acs, float* __restrict__ states)
{
    int blk = blockIdx.x;            // c*NH + h
    int h = blk % NH;
    int c = blk / NH;
    int tid = threadIdx.x;
    __shared__ float coef[T_];
    __shared__ __align__(16) float xs[32][HD];
    __shared__ float Bs[32][NS + 1];
    {
        size_t o = (size_t)blk * T_;
        float last = acs[o + T_ - 1];
        coef[tid] = expf(last - acs[o + tid]) * dt_t[o + tid];
    }
    __syncthreads();
    int tx = tid % 16;   // n0 = tx*4
    int ty = tid / 16;   // p0 = ty*8
    float acc[8][4];
    #pragma unroll
    for (int i = 0; i < 8; i++)
        #pragma unroll
        for (int j = 0; j < 4; j++) acc[i][j] = 0.f;
    size_t rowbase = (size_t)(c * T_);
    for (int t0 = 0; t0 < T_; t0 += 32) {
        #pragma unroll
        for (int i = 0; i < 4; i++) {           // xs: lane-consecutive row sweep
            int idx = tid + 256 * i;
            int r = idx >> 5, cv = idx & 31;
            float4 v = *(const float4*)(xbc + (rowbase + t0 + r) * CONVD + h * HD + cv * 4);
            *(float4*)&xs[r][cv * 4] = v;
        }
        #pragma unroll
        for (int i = 0; i < 2; i++) {           // Bs: 32x64, coef-weighted
            int idx = tid + 256 * i;
            int r = idx >> 4, cv = idx & 15;
            float4 v = *(const float4*)(xbc + (rowbase + t0 + r) * CONVD + DI + cv * 4);
            float wc = coef[t0 + r];
            Bs[r][cv*4+0] = v.x * wc; Bs[r][cv*4+1] = v.y * wc;
            Bs[r][cv*4+2] = v.z * wc; Bs[r][cv*4+3] = v.w * wc;
        }
        __syncthreads();
        #pragma unroll
        for (int tt = 0; tt < 32; tt++) {
            float xv[8], bv[4];
            #pragma unroll
            for (int i = 0; i < 8; i++) xv[i] = xs[tt][ty*8+i];
            #pragma unroll
            for (int j = 0; j < 4; j++) bv[j] = Bs[tt][tx*4+j];
            #pragma unroll
            for (int i = 0; i < 8; i++)
                #pragma unroll
                for (int j = 0; j < 4; j++)
                    acc[i][j] = fmaf(xv[i], bv[j], acc[i][j]);
        }
        __syncthreads();
    }
    size_t base = (size_t)blk * HD * NS;
    #pragma unroll
    for (int i = 0; i < 8; i++)
        #pragma unroll
        for (int j = 0; j < 4; j++)
            states[base + (size_t)(ty*8+i) * NS + tx*4+j] = acc[i][j];
}

// ---------------- in-place inter-chunk recurrence: states[c] <- prev[c] ----------------
__global__ __launch_bounds__(256) void prev_rec(
    float* __restrict__ states, const float* __restrict__ acs)
{
    int blk = blockIdx.x;          // h*4 + pq
    int pq = blk % 4;
    int h = blk / 4;
    int tid = threadIdx.x;
    int s = tid * 8;
    int p = pq * 32 + s / NS;
    int n0 = s % NS;
    float run[8];
    #pragma unroll
    for (int j = 0; j < 8; j++) run[j] = 0.f;
    for (int c = 0; c < NC; c++) {
        size_t ch = (size_t)(c * NH + h);
        size_t off = ch * HD * NS + (size_t)p * NS + n0;
        float sv[8];
        #pragma unroll
        for (int j = 0; j < 8; j++) sv[j] = states[off + j];
        #pragma unroll
        for (int j = 0; j < 8; j++) states[off + j] = run[j];
        float f = expf(acs[ch * T_ + T_ - 1]);
        #pragma unroll
        for (int j = 0; j < 8; j++) run[j] = sv[j] + f * run[j];
    }
}

// ---------------- Y = (Y_diag + Y_off + D*x) * silu(z), written over proj z-columns ----------------
// LDS: Cs[64][65] | union{ phaseA: Bs[32][65]+Ss[64][33]+xs[32][128] ; phaseB: ps[128][65] } | acs,dts
// total 12992 floats = 50.75 KB -> 3 blocks/CU
__global__ __launch_bounds__(256, 3) void y_chunk(
    const float* __restrict__ xbc, const float* __restrict__ dt_t,
    const float* __restrict__ acs, const float* __restrict__ prev,
    const float* __restrict__ D_skip, float* zy /* = proj */)
{
    int blk = blockIdx.x;          // ((c*NH)+h)*4 + qt
    int qt = blk & 3;
    int h = (blk >> 2) & 15;
    int c = blk >> 6;
    int tid = threadIdx.x;
    int tx = tid & 15;             // 0..15
    int ty = tid >> 4;             // 0..15

    __shared__ __align__(16) float smem[12992];
    float* Cs    = smem;                     // [64][65]
    float* Bsh   = smem + 4160;              // [32][65]   (phase A)
    float* Ss    = smem + 4160 + 2080;       // [64][33]
    float* xs    = smem + 4160 + 4192;       // [32][128]  (16B-aligned)
    float* ps    = smem + 4160;              // [128][65]  (phase B, aliases Bsh/Ss/xs)
    float* acs_s = smem + 12480;             // [256]
    float* dts   = smem + 12736;             // [256]

    size_t bch = (size_t)(c * NH + h);
    acs_s[tid] = acs[bch * T_ + tid];
    dts[tid]   = dt_t[bch * T_ + tid];
    size_t rowbase = (size_t)(c * T_);

    // stage Cs 64x64 (q-rows of this tile): lane-consecutive chunks
    #pragma unroll
    for (int i = 0; i < 4; i++) {
        int idx = tid + 256 * i;
        int r = idx >> 4, c4 = idx & 15;
        float4 v = *(const float4*)(xbc + (rowbase + qt*64 + r) * CONVD + DI + NS + c4 * 4);
        float* dst = Cs + r * 65 + c4 * 4;
        dst[0] = v.x; dst[1] = v.y; dst[2] = v.z; dst[3] = v.w;
    }
    __syncthreads();

    float acc[4][8];
    #pragma unroll
    for (int i = 0; i < 4; i++)
        #pragma unroll
        for (int j = 0; j < 8; j++) acc[i][j] = 0.f;

    int ntk = (qt + 1) * 2;                 // k-tiles of 32
    for (int kt = 0; kt < ntk; kt++) {
        #pragma unroll
        for (int i = 0; i < 2; i++) {       // Bs 32x64
            int idx = tid + 256 * i;
            int r = idx >> 4, c4 = idx & 15;
            float4 v = *(const float4*)(xbc + (rowbase + kt*32 + r) * CONVD + DI + c4 * 4);
            float* dst = Bsh + r * 65 + c4 * 4;
            dst[0] = v.x; dst[1] = v.y; dst[2] = v.z; dst[3] = v.w;
        }
        #pragma unroll
        for (int i = 0; i < 4; i++) {       // xs 32x128 (aligned float4)
            int idx = tid + 256 * i;
            int r = idx >> 5, c4 = idx & 31;
            float4 v = *(const float4*)(xbc + (rowbase + kt*32 + r) * CONVD + h * HD + c4 * 4);
            *(float4*)(xs + r * 128 + c4 * 4) = v;
        }
        __syncthreads();

        // scores: q = ty*4+qi, k = tx*2+ki
        {
            float sv[4][2];
            #pragma unroll
            for (int qi = 0; qi < 4; qi++) { sv[qi][0] = 0.f; sv[qi][1] = 0.f; }
            for (int n = 0; n < NS; n++) {
                float b0 = Bsh[(tx*2+0) * 65 + n];
                float b1 = Bsh[(tx*2+1) * 65 + n];
                #pragma unroll
                for (int qi = 0; qi < 4; qi++) {
                    float cq = Cs[(ty*4+qi) * 65 + n];
                    sv[qi][0] = fmaf(cq, b0, sv[qi][0]);
                    sv[qi][1] = fmaf(cq, b1, sv[qi][1]);
                }
            }
            #pragma unroll
            for (int qi = 0; qi < 4; qi++) {
                int qg = qt*64 + ty*4 + qi;
                #pragma unroll
                for (int ki = 0; ki < 2; ki++) {
                    int kg = kt*32 + tx*2 + ki;
                    float val = 0.f;
                    if (qg >= kg)
                        val = sv[qi][ki] * expf(acs_s[qg] - acs_s[kg]) * dts[kg];
                    Ss[(ty*4+qi) * 33 + tx*2 + ki] = val;
                }
            }
        }
        __syncthreads();

        // S·x: p = tx + 16j (lane-consecutive -> conflict-free)
        for (int kk = 0; kk < 32; kk++) {
            float xv[8];
            #pragma unroll
            for (int j = 0; j < 8; j++) xv[j] = xs[kk * 128 + tx + 16*j];
            #pragma unroll
            for (int qi = 0; qi < 4; qi++) {
                float sq = Ss[(ty*4+qi) * 33 + kk];
                #pragma unroll
                for (int j = 0; j < 8; j++)
                    acc[qi][j] = fmaf(sq, xv[j], acc[qi][j]);
            }
        }
        __syncthreads();
    }

    // phase B: Y_off += exp(acs[q]) * sum_n C[q,n] * prev[p,n]
    #pragma unroll
    for (int i = 0; i < 8; i++) {            // ps 128x64 -> [128][65]
        int idx = tid + 256 * i;
        int r = idx >> 4, c4 = idx & 15;
        float4 v = *(const float4*)(prev + bch * HD * NS + (size_t)r * NS + c4 * 4);
        float* dst = ps + r * 65 + c4 * 4;
        dst[0] = v.x; dst[1] = v.y; dst[2] = v.z; dst[3] = v.w;
    }
    __syncthreads();
    {
        float eq[4];
        #pragma unroll
        for (int qi = 0; qi < 4; qi++) eq[qi] = expf(acs_s[qt*64 + ty*4 + qi]);
        for (int n = 0; n < NS; n++) {
            float pv[8];
            #pragma unroll
            for (int j = 0; j < 8; j++) pv[j] = ps[(tx + 16*j) * 65 + n];
            #pragma unroll
            for (int qi = 0; qi < 4; qi++) {
                float cv = Cs[(ty*4+qi) * 65 + n] * eq[qi];
                #pragma unroll
                for (int j = 0; j < 8; j++)
                    acc[qi][j] = fmaf(cv, pv[j], acc[qi][j]);
            }
        }
    }

    float Dh = D_skip[h];
    #pragma unroll
    for (int qi = 0; qi < 4; qi++) {
        size_t row = rowbase + qt*64 + ty*4 + qi;
        const float* xr = xbc + row * CONVD + h * HD;
        float* yr = zy + row * DPROJ + h * HD;   // z lives at proj cols [0,DI)
        #pragma unroll
        for (int j = 0; j < 8; j++) {
            int p = tx + 16*j;
            float zv = yr[p];
            float g = zv / (1.f + expf(-zv));    // silu(z)
            yr[p] = (acc[qi][j] + Dh * xr[p]) * g;
        }
    }
}

extern "C" void kernel_launch(void* const* d_in, const int* in_sizes, int n_in,
                              void* d_out, int out_size, void* d_ws, size_t ws_size,
                              hipStream_t stream)
{
    const float* x       = (const float*)d_in[0];
    const float* W_in    = (const float*)d_in[1];
    const float* conv_w  = (const float*)d_in[2];
    const float* conv_b  = (const float*)d_in[3];
    const float* A_log   = (const float*)d_in[4];
    const float* dt_bias = (const float*)d_in[5];
    const float* D_skip  = (const float*)d_in[6];
    const float* W_out   = (const float*)d_in[7];
    float* out = (float*)d_out;

    // per-batch workspace (~109 MB total)
    float* proj   = (float*)d_ws;                          // L_*DPROJ
    float* xbc    = proj   + (size_t)L_ * DPROJ;           // L_*CONVD
    float* dt_t   = xbc    + (size_t)L_ * CONVD;           // NC*NH*T_
    float* acs    = dt_t   + (size_t)NC * NH * T_;
    float* states = acs    + (size_t)NC * NH * T_;         // NC*NH*HD*NS

    dim3 blk(256);
    for (int b = 0; b < B_; b++) {
        const float* xb = x + (size_t)b * L_ * DM;
        float* outb = out + (size_t)b * L_ * DM;
        sgemm_abt<<<dim3((DPROJ + 127) / 128, L_ / 128), blk, 0, stream>>>(
            xb, W_in, proj, L_, DPROJ, DM, DM, DM, DPROJ);
        conv_silu<<<dim3((unsigned)(((size_t)L_ * CONVD + 255) / 256)), blk, 0, stream>>>(
            proj, conv_w, conv_b, xbc);
        dt_scan<<<dim3(NC * NH), blk, 0, stream>>>(proj, A_log, dt_bias, dt_t, acs);
        chunk_states<<<dim3(NC * NH), blk, 0, stream>>>(xbc, dt_t, acs, states);
        prev_rec<<<dim3(NH * 4), blk, 0, stream>>>(states, acs);
        y_chunk<<<dim3(NC * NH * 4), blk, 0, stream>>>(xbc, dt_t, acs, states, D_skip, proj);
        sgemm_abt<<<dim3(DM / 128, L_ / 128), blk, 0, stream>>>(
            proj, W_out, outb, L_, DM, DI, DPROJ, DI, DM);
    }
}

// Round 4
// 2943.485 us; speedup vs baseline: 1.1539x; 1.1539x over previous
//
#include <hip/hip_runtime.h>

#define B_     2
#define L_     4096
#define DM     1024
#define DI     2048
#define NH     16
#define HD     128
#define NS     64      // D_STATE
#define T_     256     // CHUNK
#define NC     16      // L_/T_
#define CONVD  2176    // DI + 2*NS
#define DPROJ  4240    // DI + CONVD + NH

// ---------------- generic C[m,n] = sum_k A[m,k]*B[n,k] (both row-major) ----------------
__global__ __launch_bounds__(256) void sgemm_abt(
    const float* __restrict__ A, const float* __restrict__ Bm, float* __restrict__ C,
    int M, int N, int K, int lda, int ldb, int ldc)
{
    const int BM = 128, BN = 128, BK = 16;
    __shared__ __align__(16) float As[BK][BM];
    __shared__ __align__(16) float Bs[BK][BN];
    int tid = threadIdx.x;
    int m0 = blockIdx.y * BM;
    int n0 = blockIdx.x * BN;
    int ty = tid / 16, tx = tid % 16;

    float acc[8][8];
    #pragma unroll
    for (int i = 0; i < 8; i++)
        #pragma unroll
        for (int j = 0; j < 8; j++) acc[i][j] = 0.f;

    for (int k0 = 0; k0 < K; k0 += BK) {
        #pragma unroll
        for (int i = 0; i < 2; i++) {
            int f = tid * 2 + i;          // 512 float4 units
            int row = f >> 2;             // 0..127
            int colv = f & 3;             // 0..3
            float4 av = *(const float4*)(A + (size_t)(m0 + row) * lda + k0 + colv * 4);
            As[colv*4+0][row] = av.x; As[colv*4+1][row] = av.y;
            As[colv*4+2][row] = av.z; As[colv*4+3][row] = av.w;
        }
        #pragma unroll
        for (int i = 0; i < 2; i++) {
            int f = tid * 2 + i;
            int row = f >> 2;
            int colv = f & 3;
            float4 bv = make_float4(0.f, 0.f, 0.f, 0.f);
            if (n0 + row < N)
                bv = *(const float4*)(Bm + (size_t)(n0 + row) * ldb + k0 + colv * 4);
            Bs[colv*4+0][row] = bv.x; Bs[colv*4+1][row] = bv.y;
            Bs[colv*4+2][row] = bv.z; Bs[colv*4+3][row] = bv.w;
        }
        __syncthreads();
        #pragma unroll
        for (int kk = 0; kk < BK; kk++) {
            float4 a0 = *(const float4*)&As[kk][ty*8];
            float4 a1 = *(const float4*)&As[kk][ty*8+4];
            float4 b0 = *(const float4*)&Bs[kk][tx*4];
            float4 b1 = *(const float4*)&Bs[kk][64 + tx*4];
            float a[8] = {a0.x,a0.y,a0.z,a0.w,a1.x,a1.y,a1.z,a1.w};
            float b[8] = {b0.x,b0.y,b0.z,b0.w,b1.x,b1.y,b1.z,b1.w};
            #pragma unroll
            for (int i = 0; i < 8; i++)
                #pragma unroll
                for (int j = 0; j < 8; j++)
                    acc[i][j] = fmaf(a[i], b[j], acc[i][j]);
        }
        __syncthreads();
    }
    #pragma unroll
    for (int i = 0; i < 8; i++) {
        int m = m0 + ty*8 + i;
        #pragma unroll
        for (int j = 0; j < 8; j++) {
            int n = n0 + ((j < 4) ? (tx*4 + j) : (64 + tx*4 + j - 4));
            if (n < N) C[(size_t)m * ldc + n] = acc[i][j];
        }
    }
}

// ---------------- depthwise causal conv (width 4) + bias + silu; one batch ----------------
__global__ void conv_silu(const float* __restrict__ proj, const float* __restrict__ w,
                          const float* __restrict__ bias, float* __restrict__ xbc)
{
    size_t idx = (size_t)blockIdx.x * 256 + threadIdx.x;
    if (idx >= (size_t)L_ * CONVD) return;
    int c = (int)(idx % CONVD);
    int l = (int)(idx / CONVD);
    float acc = bias[c];
    #pragma unroll
    for (int j = 0; j < 4; j++) {
        int ll = l - 3 + j;
        if (ll >= 0)
            acc = fmaf(proj[(size_t)ll * DPROJ + DI + c], w[c*4+j], acc);
    }
    acc = acc / (1.f + expf(-acc));   // silu
    xbc[(size_t)l * CONVD + c] = acc;
}

// ---------------- dt = softplus(dt_raw + bias); acs = cumsum(dt*A) within 256-chunk ----------------
__global__ __launch_bounds__(256) void dt_scan(
    const float* __restrict__ proj, const float* __restrict__ A_log,
    const float* __restrict__ dt_bias, float* __restrict__ dt_t, float* __restrict__ acs)
{
    int blk = blockIdx.x;            // c*NH + h
    int h = blk % NH;
    int c = blk / NH;
    int t = threadIdx.x;
    size_t row = (size_t)(c * T_ + t);
    float raw = proj[row * DPROJ + DI + CONVD + h] + dt_bias[h];
    float dtv = (raw > 20.f) ? raw : log1pf(expf(raw));
    float Ah = -expf(A_log[h]);
    __shared__ float buf[T_];
    buf[t] = dtv * Ah;
    __syncthreads();
    for (int off = 1; off < T_; off <<= 1) {
        float add = (t >= off) ? buf[t - off] : 0.f;
        __syncthreads();
        buf[t] += add;
        __syncthreads();
    }
    size_t o = (size_t)blk * T_ + t;
    dt_t[o] = dtv;
    acs[o]  = buf[t];
}

// ---------------- per-256-chunk states[p][n] = sum_t x[t,p]*B[t,n]*exp(acs_last-acs[t])*dt[t] ----------------
__global__ __launch_bounds__(256) void chunk_states(
    const float* __restrict__ xbc, const float* __restrict__ dt_t,
    const float* __restrict__ acs, float* __restrict__ states)
{
    int blk = blockIdx.x;            // c*NH + h
    int h = blk % NH;
    int c = blk / NH;
    int tid = threadIdx.x;
    __shared__ float coef[T_];
    __shared__ __align__(16) float xs[32][HD];
    __shared__ float Bs[32][NS + 1];
    {
        size_t o = (size_t)blk * T_;
        float last = acs[o + T_ - 1];
        coef[tid] = expf(last - acs[o + tid]) * dt_t[o + tid];
    }
    __syncthreads();
    int tx = tid % 16;   // n0 = tx*4
    int ty = tid / 16;   // p0 = ty*8
    float acc[8][4];
    #pragma unroll
    for (int i = 0; i < 8; i++)
        #pragma unroll
        for (int j = 0; j < 4; j++) acc[i][j] = 0.f;
    size_t rowbase = (size_t)(c * T_);
    for (int t0 = 0; t0 < T_; t0 += 32) {
        #pragma unroll
        for (int i = 0; i < 4; i++) {
            int idx = tid + 256 * i;
            int r = idx >> 5, cv = idx & 31;
            float4 v = *(const float4*)(xbc + (rowbase + t0 + r) * CONVD + h * HD + cv * 4);
            *(float4*)&xs[r][cv * 4] = v;
        }
        #pragma unroll
        for (int i = 0; i < 2; i++) {
            int idx = tid + 256 * i;
            int r = idx >> 4, cv = idx & 15;
            float4 v = *(const float4*)(xbc + (rowbase + t0 + r) * CONVD + DI + cv * 4);
            float wc = coef[t0 + r];
            Bs[r][cv*4+0] = v.x * wc; Bs[r][cv*4+1] = v.y * wc;
            Bs[r][cv*4+2] = v.z * wc; Bs[r][cv*4+3] = v.w * wc;
        }
        __syncthreads();
        #pragma unroll
        for (int tt = 0; tt < 32; tt++) {
            float xv[8], bv[4];
            #pragma unroll
            for (int i = 0; i < 8; i++) xv[i] = xs[tt][ty*8+i];
            #pragma unroll
            for (int j = 0; j < 4; j++) bv[j] = Bs[tt][tx*4+j];
            #pragma unroll
            for (int i = 0; i < 8; i++)
                #pragma unroll
                for (int j = 0; j < 4; j++)
                    acc[i][j] = fmaf(xv[i], bv[j], acc[i][j]);
        }
        __syncthreads();
    }
    size_t base = (size_t)blk * HD * NS;
    #pragma unroll
    for (int i = 0; i < 8; i++)
        #pragma unroll
        for (int j = 0; j < 4; j++)
            states[base + (size_t)(ty*8+i) * NS + tx*4+j] = acc[i][j];
}

// ---------------- in-place inter-chunk recurrence: states[c] <- prev[c] ----------------
__global__ __launch_bounds__(256) void prev_rec(
    float* __restrict__ states, const float* __restrict__ acs)
{
    int blk = blockIdx.x;          // h*4 + pq
    int pq = blk % 4;
    int h = blk / 4;
    int tid = threadIdx.x;
    int s = tid * 8;
    int p = pq * 32 + s / NS;
    int n0 = s % NS;
    float run[8];
    #pragma unroll
    for (int j = 0; j < 8; j++) run[j] = 0.f;
    for (int c = 0; c < NC; c++) {
        size_t ch = (size_t)(c * NH + h);
        size_t off = ch * HD * NS + (size_t)p * NS + n0;
        float sv[8];
        #pragma unroll
        for (int j = 0; j < 8; j++) sv[j] = states[off + j];
        #pragma unroll
        for (int j = 0; j < 8; j++) states[off + j] = run[j];
        float f = expf(acs[ch * T_ + T_ - 1]);
        #pragma unroll
        for (int j = 0; j < 8; j++) run[j] = sv[j] + f * run[j];
    }
}

// ---------------- fused Y: per (chunk c, head h, p-quarter pq) block, sub-chunks of 32 rows ----------------
// Running state H[32][64] (this block's 32 p-rows) lives in LDS; every tile read once from global.
// Y[q] = S_local·x + exp(acs[q]-base_s)·C·H_s + D·x, gated with silu(z), written over proj z-cols.
// H_{s+1} = exp(acs_last_s-base_s)·H_s + sum_t B[t]^T (dt[t]·exp(acs_last_s-acs[t])·x[t]).
// LDS: 9184 floats = 35.9 KB -> 4 blocks/CU.
__global__ __launch_bounds__(256, 4) void y_chunk(
    const float* __restrict__ xbc, const float* __restrict__ dt_t,
    const float* __restrict__ acs, const float* __restrict__ prev,
    const float* __restrict__ D_skip, float* zy /* = proj */)
{
    int blk = blockIdx.x;          // ((c*NH)+h)*4 + pq
    int pq = blk & 3;
    int h = (blk >> 2) & 15;
    int c = blk >> 6;
    int tid = threadIdx.x;
    int tx = tid & 15;
    int ty = tid >> 4;
    int p0 = pq * 32;

    __shared__ __align__(16) float smem[9184];
    float* H     = smem;           // [32][65] = 2080  (this block's p-rows of state)
    float* Cs    = smem + 2080;    // [32][68] = 2176
    float* Bsh   = smem + 4256;    // [32][68] = 2176
    float* xs    = smem + 6432;    // [32][36] = 1152  (32 p-cols of x tile)
    float* Ss    = smem + 7584;    // [32][33] = 1056
    float* acs_s = smem + 8640;    // [256]
    float* dts   = smem + 8896;    // [256]
    float* coefs = smem + 9152;    // [32]

    size_t bch = (size_t)(c * NH + h);
    acs_s[tid] = acs[bch * T_ + tid];
    dts[tid]   = dt_t[bch * T_ + tid];
    // H init: prev[p0..p0+31][0..63]
    #pragma unroll
    for (int i = 0; i < 8; i++) {
        int idx = tid + 256 * i;
        int p = idx >> 6, n = idx & 63;
        H[p * 65 + n] = prev[bch * (HD * NS) + (size_t)(p0 + p) * NS + n];
    }
    __syncthreads();

    size_t rowbase = (size_t)(c * T_);
    float Dh = D_skip[h];

    for (int s = 0; s < 8; s++) {
        int b32 = s * 32;
        float base = (s == 0) ? 0.f : acs_s[b32 - 1];
        float aL = acs_s[b32 + 31];

        // ---- phase 1: stage Bs, Cs (full 64 n-cols), xs (this block's 32 p-cols), coefs
        #pragma unroll
        for (int i = 0; i < 2; i++) {
            int idx = tid + 256 * i;
            int r = idx >> 4, c4 = idx & 15;
            float4 v = *(const float4*)(xbc + (rowbase + b32 + r) * CONVD + DI + c4 * 4);
            *(float4*)&Bsh[r * 68 + c4 * 4] = v;
            float4 u = *(const float4*)(xbc + (rowbase + b32 + r) * CONVD + DI + NS + c4 * 4);
            *(float4*)&Cs[r * 68 + c4 * 4] = u;
        }
        {
            int r = tid >> 3, c4 = tid & 7;
            float4 v = *(const float4*)(xbc + (rowbase + b32 + r) * CONVD + h * HD + p0 + c4 * 4);
            *(float4*)&xs[r * 36 + c4 * 4] = v;
        }
        if (tid < 32)
            coefs[tid] = dts[b32 + tid] * expf(aL - acs_s[b32 + tid]);
        __syncthreads();

        // ---- phase 2: S[q][k] = (C·B)·exp(acs[q]-acs[k])·dt[k], masked q>=k (local 32x32)
        {
            float sv[2][2] = {{0.f,0.f},{0.f,0.f}};
            for (int n = 0; n < NS; n++) {
                float cq0 = Cs[(ty*2+0) * 68 + n];
                float cq1 = Cs[(ty*2+1) * 68 + n];
                float bk0 = Bsh[(tx*2+0) * 68 + n];
                float bk1 = Bsh[(tx*2+1) * 68 + n];
                sv[0][0] = fmaf(cq0, bk0, sv[0][0]);
                sv[0][1] = fmaf(cq0, bk1, sv[0][1]);
                sv[1][0] = fmaf(cq1, bk0, sv[1][0]);
                sv[1][1] = fmaf(cq1, bk1, sv[1][1]);
            }
            #pragma unroll
            for (int qi = 0; qi < 2; qi++) {
                int ql = ty*2 + qi;
                #pragma unroll
                for (int ki = 0; ki < 2; ki++) {
                    int kl = tx*2 + ki;
                    float val = 0.f;
                    if (ql >= kl)
                        val = sv[qi][ki] * expf(acs_s[b32+ql] - acs_s[b32+kl]) * dts[b32+kl];
                    Ss[ql * 33 + kl] = val;
                }
            }
        }
        __syncthreads();

        // ---- phase 3: Y = S·x + eq·(C·H) + D·x, gate, write
        {
            float acc[2][2] = {{0.f,0.f},{0.f,0.f}};
            for (int kk = 0; kk < 32; kk++) {
                float s0 = Ss[(ty*2+0) * 33 + kk];
                float s1 = Ss[(ty*2+1) * 33 + kk];
                float x0 = xs[kk * 36 + tx*2 + 0];
                float x1 = xs[kk * 36 + tx*2 + 1];
                acc[0][0] = fmaf(s0, x0, acc[0][0]);
                acc[0][1] = fmaf(s0, x1, acc[0][1]);
                acc[1][0] = fmaf(s1, x0, acc[1][0]);
                acc[1][1] = fmaf(s1, x1, acc[1][1]);
            }
            float eq0 = expf(acs_s[b32 + ty*2 + 0] - base);
            float eq1 = expf(acs_s[b32 + ty*2 + 1] - base);
            for (int n = 0; n < NS; n++) {
                float c0 = Cs[(ty*2+0) * 68 + n] * eq0;
                float c1 = Cs[(ty*2+1) * 68 + n] * eq1;
                float h0 = H[(tx*2+0) * 65 + n];
                float h1 = H[(tx*2+1) * 65 + n];
                acc[0][0] = fmaf(c0, h0, acc[0][0]);
                acc[0][1] = fmaf(c0, h1, acc[0][1]);
                acc[1][0] = fmaf(c1, h0, acc[1][0]);
                acc[1][1] = fmaf(c1, h1, acc[1][1]);
            }
            #pragma unroll
            for (int qi = 0; qi < 2; qi++) {
                int ql = ty*2 + qi;
                size_t row = rowbase + b32 + ql;
                float xq0 = xs[ql * 36 + tx*2 + 0];
                float xq1 = xs[ql * 36 + tx*2 + 1];
                float* yr = zy + row * DPROJ + h * HD + p0 + tx*2;
                float z0 = yr[0], z1 = yr[1];
                yr[0] = (acc[qi][0] + Dh * xq0) * (z0 / (1.f + expf(-z0)));
                yr[1] = (acc[qi][1] + Dh * xq1) * (z1 / (1.f + expf(-z1)));
            }
        }
        __syncthreads();   // all H reads done

        // ---- phase 4: H <- decay·H + B^T(coef·x)   (p = ty*2+i rows, n = tx*4+j cols)
        {
            float decay = expf(aL - base);
            float hreg[2][4];
            #pragma unroll
            for (int i = 0; i < 2; i++)
                #pragma unroll
                for (int j = 0; j < 4; j++)
                    hreg[i][j] = H[(ty*2+i) * 65 + tx*4 + j] * decay;
            for (int t = 0; t < 32; t++) {
                float cf = coefs[t];
                float b0 = Bsh[t * 68 + tx*4 + 0];
                float b1 = Bsh[t * 68 + tx*4 + 1];
                float b2 = Bsh[t * 68 + tx*4 + 2];
                float b3 = Bsh[t * 68 + tx*4 + 3];
                float xa = xs[t * 36 + ty*2 + 0] * cf;
                float xb = xs[t * 36 + ty*2 + 1] * cf;
                hreg[0][0] = fmaf(xa, b0, hreg[0][0]);
                hreg[0][1] = fmaf(xa, b1, hreg[0][1]);
                hreg[0][2] = fmaf(xa, b2, hreg[0][2]);
                hreg[0][3] = fmaf(xa, b3, hreg[0][3]);
                hreg[1][0] = fmaf(xb, b0, hreg[1][0]);
                hreg[1][1] = fmaf(xb, b1, hreg[1][1]);
                hreg[1][2] = fmaf(xb, b2, hreg[1][2]);
                hreg[1][3] = fmaf(xb, b3, hreg[1][3]);
            }
            #pragma unroll
            for (int i = 0; i < 2; i++)
                #pragma unroll
                for (int j = 0; j < 4; j++)
                    H[(ty*2+i) * 65 + tx*4 + j] = hreg[i][j];
        }
        __syncthreads();
    }
}

extern "C" void kernel_launch(void* const* d_in, const int* in_sizes, int n_in,
                              void* d_out, int out_size, void* d_ws, size_t ws_size,
                              hipStream_t stream)
{
    const float* x       = (const float*)d_in[0];
    const float* W_in    = (const float*)d_in[1];
    const float* conv_w  = (const float*)d_in[2];
    const float* conv_b  = (const float*)d_in[3];
    const float* A_log   = (const float*)d_in[4];
    const float* dt_bias = (const float*)d_in[5];
    const float* D_skip  = (const float*)d_in[6];
    const float* W_out   = (const float*)d_in[7];
    float* out = (float*)d_out;

    // per-batch workspace (~109 MB total)
    float* proj   = (float*)d_ws;                          // L_*DPROJ
    float* xbc    = proj   + (size_t)L_ * DPROJ;           // L_*CONVD
    float* dt_t   = xbc    + (size_t)L_ * CONVD;           // NC*NH*T_
    float* acs    = dt_t   + (size_t)NC * NH * T_;
    float* states = acs    + (size_t)NC * NH * T_;         // NC*NH*HD*NS

    dim3 blk(256);
    for (int b = 0; b < B_; b++) {
        const float* xb = x + (size_t)b * L_ * DM;
        float* outb = out + (size_t)b * L_ * DM;
        sgemm_abt<<<dim3((DPROJ + 127) / 128, L_ / 128), blk, 0, stream>>>(
            xb, W_in, proj, L_, DPROJ, DM, DM, DM, DPROJ);
        conv_silu<<<dim3((unsigned)(((size_t)L_ * CONVD + 255) / 256)), blk, 0, stream>>>(
            proj, conv_w, conv_b, xbc);
        dt_scan<<<dim3(NC * NH), blk, 0, stream>>>(proj, A_log, dt_bias, dt_t, acs);
        chunk_states<<<dim3(NC * NH), blk, 0, stream>>>(xbc, dt_t, acs, states);
        prev_rec<<<dim3(NH * 4), blk, 0, stream>>>(states, acs);
        y_chunk<<<dim3(NC * NH * 4), blk, 0, stream>>>(xbc, dt_t, acs, states, D_skip, proj);
        sgemm_abt<<<dim3(DM / 128, L_ / 128), blk, 0, stream>>>(
            proj, W_out, outb, L_, DM, DI, DPROJ, DI, DM);
    }
}